// Round 4
// baseline (718.452 us; speedup 1.0000x reference)
//
#include <hip/hip_runtime.h>
#include <math.h>

#define NGENES 50000
#define NEDGES 5000
#define NNZ_C 1600000
#define NPATH 500
#define DIM 128
#define BB 64
#define MM 200
#define BMN (BB * MM)
#define NBMW 1568          // bitmap words (50176 bits >= 50000)
#define CSRCAP 768000      // marked CSR entries ~410K expected
#define NCH 32             // histogram chunks
#define RNG 12512          // gene range per histogram role (4*12512 = 50048)
#define GSTRIDE 50048      // partial row stride

// ---------------- wave helpers ----------------
__device__ inline float wred_sum(float x) {
#pragma unroll
  for (int off = 32; off > 0; off >>= 1) x += __shfl_down(x, off, 64);
  return x;
}
__device__ inline float wred_max(float x) {
#pragma unroll
  for (int off = 32; off > 0; off >>= 1) x = fmaxf(x, __shfl_down(x, off, 64));
  return x;
}
__device__ inline int wave_incl_scan(int x) {
  int lane = threadIdx.x & 63;
#pragma unroll
  for (int off = 1; off < 64; off <<= 1) {
    int y = __shfl_up(x, off, 64);
    if (lane >= off) x += y;
  }
  return x;
}

// mark genes referenced by gene_ids in a bitmap
__global__ void k_mark(const int* __restrict__ gene_ids, unsigned* __restrict__ bitmap) {
  int i = blockIdx.x * blockDim.x + threadIdx.x;
  if (i >= BMN) return;
  int g = gene_ids[i];
  atomicOr(bitmap + (g >> 5), 1u << (g & 31));
}

// Unified atomic-free histogram. grid = (NCH chunks, 9 roles), 1024 threads.
// roles 0-3: Dv fp32 LDS histogram over gene range [role*RNG, +RNG)
// roles 4-7: marked-gene count histogram over same ranges
// role  8  : col cnt + sum histogram (5000 bins)
// Each block writes its full partial slice to global (coalesced) — NO global atomics.
__global__ void k_hist_all(const int* __restrict__ rows, const int* __restrict__ cols,
                           const float* __restrict__ vals, const unsigned* __restrict__ bitmap,
                           float* __restrict__ pdv, int* __restrict__ pcnt,
                           int* __restrict__ pccnt, float* __restrict__ pcsum) {
  __shared__ char smem_raw[RNG * 4 + NBMW * 4];  // 56,320 B
  int c = blockIdx.x;
  int role = blockIdx.y;
  int tid = threadIdx.x;
  int lo = c * (NNZ_C / NCH);
  int hi = lo + (NNZ_C / NCH);
  if (role < 4) {
    float* hs = (float*)smem_raw;
    int rlo = role * RNG;
    for (int j = tid; j < RNG; j += 1024) hs[j] = 0.f;
    __syncthreads();
    for (int i = lo + tid; i < hi; i += 1024) {
      int r = rows[i];
      unsigned d = (unsigned)(r - rlo);
      if (d < RNG) atomicAdd(&hs[d], vals[i]);
    }
    __syncthreads();
    float* dst = pdv + (size_t)c * GSTRIDE + rlo;
    for (int j = tid; j < RNG; j += 1024) dst[j] = hs[j];
  } else if (role < 8) {
    int* hs = (int*)smem_raw;
    unsigned* bm = (unsigned*)(smem_raw + RNG * 4);
    int rlo = (role - 4) * RNG;
    for (int j = tid; j < RNG; j += 1024) hs[j] = 0;
    for (int j = tid; j < NBMW; j += 1024) bm[j] = bitmap[j];
    __syncthreads();
    for (int i = lo + tid; i < hi; i += 1024) {
      int r = rows[i];
      unsigned d = (unsigned)(r - rlo);
      if (d < RNG && ((bm[r >> 5] >> (r & 31)) & 1)) atomicAdd(&hs[d], 1);
    }
    __syncthreads();
    int* dst = pcnt + (size_t)c * GSTRIDE + rlo;
    for (int j = tid; j < RNG; j += 1024) dst[j] = hs[j];
  } else {
    int* hc = (int*)smem_raw;
    float* hsum = (float*)(smem_raw + NEDGES * 4);
    for (int j = tid; j < NEDGES; j += 1024) { hc[j] = 0; hsum[j] = 0.f; }
    __syncthreads();
    for (int i = lo + tid; i < hi; i += 1024) {
      int cc = cols[i];
      float v = vals[i];
      atomicAdd(&hc[cc], 1);
      atomicAdd(&hsum[cc], v);
    }
    __syncthreads();
    for (int j = tid; j < NEDGES; j += 1024) {
      pccnt[c * NEDGES + j] = hc[j];
      pcsum[c * NEDGES + j] = hsum[j];
    }
  }
}

__global__ void k_reduce_gene(const float* __restrict__ pdv, const int* __restrict__ pcnt,
                              float* __restrict__ Dv, int* __restrict__ row_cnt) {
  int g = blockIdx.x * 256 + threadIdx.x;
  if (g >= NGENES) return;
  float s = 0.f;
  int n = 0;
  for (int c = 0; c < NCH; ++c) {
    s += pdv[(size_t)c * GSTRIDE + g];
    n += pcnt[(size_t)c * GSTRIDE + g];
  }
  Dv[g] = s;
  row_cnt[g] = n;
}

__global__ void k_reduce_col(const int* __restrict__ pccnt, const float* __restrict__ pcsum,
                             float* __restrict__ De, int* __restrict__ col_cnt) {
  int e = blockIdx.x * 256 + threadIdx.x;
  if (e >= NEDGES) return;
  float s = 0.f;
  int n = 0;
  for (int c = 0; c < NCH; ++c) {
    n += pccnt[c * NEDGES + e];
    s += pcsum[c * NEDGES + e];
  }
  De[e] = s;
  col_cnt[e] = n;
}

// blocked single-block exclusive scan: thread t owns ceil(n/1024) consecutive elems
__global__ void k_scan_excl(const int* __restrict__ in, int* __restrict__ out, int n) {
  __shared__ int wsum[16];
  int t = threadIdx.x, lane = t & 63, wid = t >> 6;
  int nper = (n + 1023) / 1024;
  int base_i = t * nper;
  int s = 0;
  for (int j = 0; j < nper; ++j) {
    int i = base_i + j;
    if (i < n) s += in[i];
  }
  int incl = wave_incl_scan(s);
  if (lane == 63) wsum[wid] = incl;
  __syncthreads();
  int woff = 0;
  for (int w = 0; w < wid; ++w) woff += wsum[w];
  int run = woff + incl - s;
  for (int j = 0; j < nper; ++j) {
    int i = base_i + j;
    if (i < n) {
      out[i] = run;
      run += in[i];
    }
  }
}

// placement: CSC via two-phase LDS reservation; CSR only for marked rows. Packed int2.
__global__ void k_place(const int* __restrict__ rows, const int* __restrict__ cols,
                        const float* __restrict__ vals, const float* __restrict__ Dv,
                        const int* __restrict__ col_start, int* __restrict__ col_cur,
                        const int* __restrict__ row_start, int* __restrict__ row_cur,
                        const unsigned* __restrict__ bitmap,
                        int2* __restrict__ csc, int2* __restrict__ csr) {
  __shared__ int cnt_s[NEDGES];
  __shared__ int base_s[NEDGES];
  __shared__ unsigned bm_s[NBMW];
  int tid = threadIdx.x;
  for (int i = tid; i < NEDGES; i += 512) cnt_s[i] = 0;
  for (int i = tid; i < NBMW; i += 512) bm_s[i] = bitmap[i];
  __syncthreads();
  const int chunk = (NNZ_C + gridDim.x - 1) / gridDim.x;
  int lo = blockIdx.x * chunk;
  int hi = min(lo + chunk, NNZ_C);
  for (int i = lo + tid; i < hi; i += 512) atomicAdd(&cnt_s[cols[i]], 1);
  __syncthreads();
  for (int c = tid; c < NEDGES; c += 512) {
    int n = cnt_s[c];
    if (n) {
      base_s[c] = col_start[c] + atomicAdd(col_cur + c, n);
      cnt_s[c] = 0;
    }
  }
  __syncthreads();
  for (int i = lo + tid; i < hi; i += 512) {
    int r = rows[i], c = cols[i];
    float v = vals[i];
    float w = v / sqrtf(Dv[r] + 1e-6f);
    int pos = base_s[c] + atomicAdd(&cnt_s[c], 1);
    csc[pos] = make_int2(r, __float_as_int(w));
    if ((bm_s[r >> 5] >> (r & 31)) & 1) {
      int p2 = row_start[r] + atomicAdd(row_cur + r, 1);
      if (p2 < CSRCAP) csr[p2] = make_int2(c, __float_as_int(v));
    }
  }
}

// pass B: HXde[e,:] = (1/(De[e]+1e-6)) * sum_i w_i * gene_embed[r_i,:]
// 256 threads = 8 half-wave groups; 4-deep unroll = 32 gathers in flight per block.
__global__ void k_edge(const int* __restrict__ col_start, const int2* __restrict__ csc,
                       const float* __restrict__ gene_embed, const float* __restrict__ De,
                       float* __restrict__ HXde) {
  __shared__ float4 red[8][32];
  int e = blockIdx.x;
  int s = col_start[e];
  int end = (e == NEDGES - 1) ? NNZ_C : col_start[e + 1];
  int g = threadIdx.x >> 5, l = threadIdx.x & 31;
  float4 a0 = make_float4(0.f, 0.f, 0.f, 0.f);
  float4 a1 = make_float4(0.f, 0.f, 0.f, 0.f);
  float4 a2 = make_float4(0.f, 0.f, 0.f, 0.f);
  float4 a3 = make_float4(0.f, 0.f, 0.f, 0.f);
  int i = s + g;
  for (; i + 24 < end; i += 32) {
    int2 e0 = csc[i];
    int2 e1 = csc[i + 8];
    int2 e2 = csc[i + 16];
    int2 e3 = csc[i + 24];
    float4 x0 = *((const float4*)(gene_embed + (size_t)e0.x * DIM) + l);
    float4 x1 = *((const float4*)(gene_embed + (size_t)e1.x * DIM) + l);
    float4 x2 = *((const float4*)(gene_embed + (size_t)e2.x * DIM) + l);
    float4 x3 = *((const float4*)(gene_embed + (size_t)e3.x * DIM) + l);
    float w0 = __int_as_float(e0.y), w1 = __int_as_float(e1.y);
    float w2 = __int_as_float(e2.y), w3 = __int_as_float(e3.y);
    a0.x += w0 * x0.x; a0.y += w0 * x0.y; a0.z += w0 * x0.z; a0.w += w0 * x0.w;
    a1.x += w1 * x1.x; a1.y += w1 * x1.y; a1.z += w1 * x1.z; a1.w += w1 * x1.w;
    a2.x += w2 * x2.x; a2.y += w2 * x2.y; a2.z += w2 * x2.z; a2.w += w2 * x2.w;
    a3.x += w3 * x3.x; a3.y += w3 * x3.y; a3.z += w3 * x3.z; a3.w += w3 * x3.w;
  }
  for (; i < end; i += 8) {
    int2 en = csc[i];
    float w = __int_as_float(en.y);
    float4 x = *((const float4*)(gene_embed + (size_t)en.x * DIM) + l);
    a0.x += w * x.x; a0.y += w * x.y; a0.z += w * x.z; a0.w += w * x.w;
  }
  a0.x += a1.x + a2.x + a3.x;
  a0.y += a1.y + a2.y + a3.y;
  a0.z += a1.z + a2.z + a3.z;
  a0.w += a1.w + a2.w + a3.w;
  red[g][l] = a0;
  __syncthreads();
  if (g == 0) {
    float4 o = red[0][l];
#pragma unroll
    for (int gg = 1; gg < 8; ++gg) {
      float4 t = red[gg][l];
      o.x += t.x; o.y += t.y; o.z += t.z; o.w += t.w;
    }
    float inv = 1.f / (De[e] + 1e-6f);
    o.x *= inv; o.y *= inv; o.z *= inv; o.w *= inv;
    *((float4*)(HXde + (size_t)e * DIM) + l) = o;
  }
}

// pass C fused with gene_ids gather (partial CSR); 4 groups, 2-deep unroll
__global__ void k_gene(const int* __restrict__ gene_ids, const int* __restrict__ row_start,
                       const int* __restrict__ row_cnt, const int2* __restrict__ csr,
                       const float* __restrict__ HXde, const float* __restrict__ Dv,
                       float* __restrict__ Xg) {
  __shared__ float4 red[4][32];
  int bm = blockIdx.x;
  int gene = gene_ids[bm];
  int s = row_start[gene], n = row_cnt[gene];
  int end = s + n;
  int g = threadIdx.x >> 5, l = threadIdx.x & 31;
  float4 a0 = make_float4(0.f, 0.f, 0.f, 0.f);
  float4 a1 = make_float4(0.f, 0.f, 0.f, 0.f);
  int i = s + g;
  for (; i + 4 < end; i += 8) {
    int2 e0 = csr[i];
    int2 e1 = csr[i + 4];
    float4 x0 = *((const float4*)(HXde + (size_t)e0.x * DIM) + l);
    float4 x1 = *((const float4*)(HXde + (size_t)e1.x * DIM) + l);
    float v0 = __int_as_float(e0.y), v1 = __int_as_float(e1.y);
    a0.x += v0 * x0.x; a0.y += v0 * x0.y; a0.z += v0 * x0.z; a0.w += v0 * x0.w;
    a1.x += v1 * x1.x; a1.y += v1 * x1.y; a1.z += v1 * x1.z; a1.w += v1 * x1.w;
  }
  for (; i < end; i += 4) {
    int2 en = csr[i];
    float v = __int_as_float(en.y);
    float4 x = *((const float4*)(HXde + (size_t)en.x * DIM) + l);
    a0.x += v * x.x; a0.y += v * x.y; a0.z += v * x.z; a0.w += v * x.w;
  }
  a0.x += a1.x; a0.y += a1.y; a0.z += a1.z; a0.w += a1.w;
  red[g][l] = a0;
  __syncthreads();
  if (g == 0) {
    float4 a = red[0][l], b = red[1][l], c = red[2][l], d = red[3][l];
    float dvg = 1.f / sqrtf(Dv[gene] + 1e-6f);
    float4 o;
    o.x = (a.x + b.x + c.x + d.x) * dvg;
    o.y = (a.y + b.y + c.y + d.y) * dvg;
    o.z = (a.z + b.z + c.z + d.z) * dvg;
    o.w = (a.w + b.w + c.w + d.w) * dvg;
    *((float4*)(Xg + (size_t)bm * DIM) + l) = o;
  }
}

// rep[b,p,d] = (sum_m Xg[b,m,d]*mask[m,p]) / max(cnt[p],1)
#define PT 20
__global__ void k_pathway(const int* __restrict__ gene_ids,
                          const float* __restrict__ gene_pathway,
                          const float* __restrict__ Xg, float* __restrict__ rep) {
  int b = blockIdx.y;
  int p0 = blockIdx.x * PT;
  int d = threadIdx.x;
  float acc[PT], cnt[PT];
#pragma unroll
  for (int pp = 0; pp < PT; ++pp) { acc[pp] = 0.f; cnt[pp] = 0.f; }
  for (int m = 0; m < MM; ++m) {
    int g = gene_ids[b * MM + m];
    float x = Xg[(size_t)(b * MM + m) * DIM + d];
    const float* mrow = gene_pathway + (size_t)g * NPATH + p0;
#pragma unroll
    for (int pp = 0; pp < PT; ++pp) {
      float mv = mrow[pp];
      acc[pp] += mv * x;
      cnt[pp] += mv;
    }
  }
#pragma unroll
  for (int pp = 0; pp < PT; ++pp) {
    rep[((size_t)b * NPATH + p0 + pp) * DIM + d] = acc[pp] / fmaxf(cnt[pp], 1.f);
  }
}

// ctxW[b,j] = sum_k ctx[b,k] * W1[D+k, j]
__global__ void k_ctxw(const int* __restrict__ context_ids,
                       const float* __restrict__ treatment_embed,
                       const float* __restrict__ W1, float* __restrict__ ctxW) {
  __shared__ float ctx_s[DIM];
  int b = blockIdx.x, j = threadIdx.x;
  ctx_s[j] = treatment_embed[context_ids[b] * DIM + j];
  __syncthreads();
  float acc = 0.f;
  for (int k = 0; k < DIM; ++k) acc += ctx_s[k] * W1[(DIM + k) * DIM + j];
  ctxW[b * DIM + j] = acc;
}

// scores[b,p] = tanh(rep@W1_top + ctxW + b1) @ W2 + b2
#define PT2 10
__global__ void k_attn(const float* __restrict__ rep, const float* __restrict__ ctxW,
                       const float* __restrict__ W1, const float* __restrict__ b1,
                       const float* __restrict__ W2, const float* __restrict__ b2,
                       float* __restrict__ scores) {
  __shared__ float in_s[PT2][DIM];
  __shared__ float part[PT2][2];
  int b = blockIdx.y;
  int p0 = blockIdx.x * PT2;
  int j = threadIdx.x;
  int lane = j & 63, wid = j >> 6;
#pragma unroll
  for (int pp = 0; pp < PT2; ++pp)
    in_s[pp][j] = rep[((size_t)b * NPATH + p0 + pp) * DIM + j];
  __syncthreads();
  float base = b1[j] + ctxW[b * DIM + j];
  float acc[PT2];
#pragma unroll
  for (int pp = 0; pp < PT2; ++pp) acc[pp] = base;
  for (int k = 0; k < DIM; ++k) {
    float w1 = W1[k * DIM + j];
#pragma unroll
    for (int pp = 0; pp < PT2; ++pp) acc[pp] += in_s[pp][k] * w1;
  }
  float w2 = W2[j];
#pragma unroll
  for (int pp = 0; pp < PT2; ++pp) {
    float t = tanhf(acc[pp]) * w2;
    t = wred_sum(t);
    if (lane == 0) part[pp][wid] = t;
  }
  __syncthreads();
  if (j < PT2) scores[b * NPATH + p0 + j] = part[j][0] + part[j][1] + b2[0];
}

// softmax + z0 + z + risk, one block per b (128 threads)
__global__ void k_final(const float* __restrict__ scores, const float* __restrict__ rep,
                        const float* __restrict__ latent_W, const float* __restrict__ latent_b,
                        const float* __restrict__ risk_W, const float* __restrict__ risk_b,
                        float* __restrict__ out) {
  __shared__ float w_s[NPATH];
  __shared__ float z0_s[DIM];
  __shared__ float red_max[2], red_sum[2], red_risk[2];
  int b = blockIdx.x, t = threadIdx.x;
  int lane = t & 63, wid = t >> 6;
  float lmax = -3.4e38f;
  for (int p = t; p < NPATH; p += 128) {
    float s = scores[b * NPATH + p];
    w_s[p] = s;
    lmax = fmaxf(lmax, s);
  }
  lmax = wred_max(lmax);
  if (lane == 0) red_max[wid] = lmax;
  __syncthreads();
  float bmax = fmaxf(red_max[0], red_max[1]);
  float lsum = 0.f;
  for (int p = t; p < NPATH; p += 128) {
    float e = expf(w_s[p] - bmax);
    w_s[p] = e;
    lsum += e;
  }
  lsum = wred_sum(lsum);
  if (lane == 0) red_sum[wid] = lsum;
  __syncthreads();
  float inv = 1.f / (red_sum[0] + red_sum[1]);
  float z0 = 0.f;
  int d = t;
#pragma unroll 4
  for (int p = 0; p < NPATH; ++p) z0 += w_s[p] * rep[((size_t)b * NPATH + p) * DIM + d];
  z0 *= inv;
  z0_s[d] = z0;
  __syncthreads();
  float z = latent_b[t];
  for (int dd = 0; dd < DIM; ++dd) z += z0_s[dd] * latent_W[dd * DIM + t];
  out[BB + b * DIM + t] = z;
  float r = z * risk_W[t];
  r = wred_sum(r);
  if (lane == 0) red_risk[wid] = r;
  __syncthreads();
  if (t == 0) out[b] = red_risk[0] + red_risk[1] + risk_b[0];
}

extern "C" void kernel_launch(void* const* d_in, const int* in_sizes, int n_in,
                              void* d_out, int out_size, void* d_ws, size_t ws_size,
                              hipStream_t stream) {
  const int* gene_ids = (const int*)d_in[0];
  const int* context_ids = (const int*)d_in[1];
  const int* H_rows = (const int*)d_in[2];
  const int* H_cols = (const int*)d_in[3];
  const float* H_vals = (const float*)d_in[4];
  const float* gene_embed = (const float*)d_in[5];
  const float* treatment_embed = (const float*)d_in[6];
  const float* gene_pathway = (const float*)d_in[7];
  const float* W1 = (const float*)d_in[8];
  const float* b1 = (const float*)d_in[9];
  const float* W2 = (const float*)d_in[10];
  const float* b2 = (const float*)d_in[11];
  const float* latent_W = (const float*)d_in[12];
  const float* latent_b = (const float*)d_in[13];
  const float* risk_W = (const float*)d_in[14];
  const float* risk_b = (const float*)d_in[15];
  float* out = (float*)d_out;

  char* ws = (char*)d_ws;
  float* Dv = (float*)(ws + 0);                // 50000 f
  float* De = (float*)(ws + 200000);           // 5000 f
  int* col_cnt = (int*)(ws + 220000);          // 5000 i
  int* row_cnt = (int*)(ws + 240000);          // 50000 i
  int* col_start = (int*)(ws + 440000);        // 5000 i
  int* row_start = (int*)(ws + 460000);        // 50000 i
  int* col_cur = (int*)(ws + 660000);          // 5000 i   [memset]
  int* row_cur = (int*)(ws + 680000);          // 50000 i  [memset]
  unsigned* bitmap = (unsigned*)(ws + 880000); // 1568 u32 [memset] -> 886272
  int2* csc = (int2*)(ws + 886272);            // 1.6M int2 -> 13686272
  int2* csr = (int2*)(ws + 13686272);          // 768K int2 -> 19830272
  // partial histograms ALIAS csc/csr region (dead before k_place writes them):
  float* pdv = (float*)(ws + 886272);          // [32][50048] f -> 7292416
  int* pcnt = (int*)(ws + 7292416);            // [32][50048] i -> 13698560
  int* pccnt = (int*)(ws + 13698560);          // [32][5000] i -> 14338560
  float* pcsum = (float*)(ws + 14338560);      // [32][5000] f -> 14978560 (< 19830272 OK)
  float* HXde = (float*)(ws + 19830272);       // 5000*128 -> 22390272
  float* Xg = (float*)(ws + 22390272);         // 12800*128 -> 28943872
  float* rep = (float*)(ws + 28943872);        // 64*500*128 -> 45327872
  float* scores = (float*)(ws + 45327872);     // 64*500 -> 45455872
  float* ctxW = (float*)(ws + 45455872);       // 64*128 -> 45488640

  hipMemsetAsync(ws + 660000, 0, 226272, stream);  // col_cur, row_cur, bitmap

  k_mark<<<(BMN + 255) / 256, 256, 0, stream>>>(gene_ids, bitmap);
  k_hist_all<<<dim3(NCH, 9), 1024, 0, stream>>>(H_rows, H_cols, H_vals, bitmap,
                                                pdv, pcnt, pccnt, pcsum);
  k_reduce_gene<<<(NGENES + 255) / 256, 256, 0, stream>>>(pdv, pcnt, Dv, row_cnt);
  k_reduce_col<<<(NEDGES + 255) / 256, 256, 0, stream>>>(pccnt, pcsum, De, col_cnt);
  k_scan_excl<<<1, 1024, 0, stream>>>(col_cnt, col_start, NEDGES);
  k_scan_excl<<<1, 1024, 0, stream>>>(row_cnt, row_start, NGENES);
  k_place<<<128, 512, 0, stream>>>(H_rows, H_cols, H_vals, Dv, col_start, col_cur,
                                   row_start, row_cur, bitmap, csc, csr);
  k_edge<<<NEDGES, 256, 0, stream>>>(col_start, csc, gene_embed, De, HXde);
  k_gene<<<BMN, 128, 0, stream>>>(gene_ids, row_start, row_cnt, csr, HXde, Dv, Xg);
  k_pathway<<<dim3(NPATH / PT, BB), DIM, 0, stream>>>(gene_ids, gene_pathway, Xg, rep);
  k_ctxw<<<BB, DIM, 0, stream>>>(context_ids, treatment_embed, W1, ctxW);
  k_attn<<<dim3(NPATH / PT2, BB), DIM, 0, stream>>>(rep, ctxW, W1, b1, W2, b2, scores);
  k_final<<<BB, DIM, 0, stream>>>(scores, rep, latent_W, latent_b, risk_W, risk_b, out);
}